// Round 10
// baseline (581.241 us; speedup 1.0000x reference)
//
#include <hip/hip_runtime.h>

#define M_DIM 8192
#define K_DIM 4096
#define N_DIM 11008
#define XSCALE 20.0f

typedef int i32x4  __attribute__((ext_vector_type(4)));
typedef unsigned char uchar;

// ---------- pre-pass 1: x fp32 -> i8 (round(x*20), clamp +-127) + exact int row sums ----------
__global__ __launch_bounds__(256) void k_quant_x(const float4* __restrict__ x,
                                                 int4* __restrict__ xq,
                                                 float* __restrict__ rs) {
    __shared__ int sred[4];
    const int row = blockIdx.x;
    const int t = threadIdx.x;
    const float4* src = x + (size_t)row * (K_DIM / 4) + t * 4;
    int o[4];
    int acc = 0;
#pragma unroll
    for (int c = 0; c < 4; ++c) {
        float4 v = src[c];
        int b0 = __float2int_rn(fmaxf(fminf(v.x * XSCALE, 127.f), -127.f));
        int b1 = __float2int_rn(fmaxf(fminf(v.y * XSCALE, 127.f), -127.f));
        int b2 = __float2int_rn(fmaxf(fminf(v.z * XSCALE, 127.f), -127.f));
        int b3 = __float2int_rn(fmaxf(fminf(v.w * XSCALE, 127.f), -127.f));
        acc += b0 + b1 + b2 + b3;
        o[c] = (b0 & 255) | ((b1 & 255) << 8) | ((b2 & 255) << 16) | ((b3 & 255) << 24);
    }
    xq[(size_t)row * 256 + t] = make_int4(o[0], o[1], o[2], o[3]);
#pragma unroll
    for (int off = 32; off >= 1; off >>= 1) acc += __shfl_down(acc, off);
    if ((t & 63) == 0) sred[t >> 6] = acc;
    __syncthreads();
    if (t == 0) rs[row] = (float)(sred[0] + sred[1] + sred[2] + sred[3]);
}

// ---------- pre-pass 2: qweight int32 (0..15) -> packed i8 ----------
__global__ __launch_bounds__(256) void k_pack_w(const int4* __restrict__ q, int4* __restrict__ wq) {
    size_t i = (size_t)blockIdx.x * 256 + threadIdx.x;   // 16 elems per thread
    int4 a = q[i * 4], b = q[i * 4 + 1], c = q[i * 4 + 2], d = q[i * 4 + 3];
    int4 o;
    o.x = a.x | (a.y << 8) | (a.z << 16) | (a.w << 24);
    o.y = b.x | (b.y << 8) | (b.z << 16) | (b.w << 24);
    o.z = c.x | (c.y << 8) | (c.z << 16) | (c.w << 24);
    o.w = d.x | (d.y << 8) | (d.z << 16) | (d.w << 24);
    wq[i] = o;
}

// ---------- 256x256 i8 GEMM, BK=64, 4-deep LDS ring, lead-1 counted-lgkm schedule ----------
// S[m][n] = sum_k X[m][k]*Q[n][k] (exact);  y = (s/20)*S - (s*zp/20)*RS[m] + bias
// LDS: per tile A 16KB + B 16KB, 4 tiles resident (128 KB). Tile t+1 is resident one full
// tile before use -> its ds_reads issue one WINDOW early; counted lgkmcnt(4) drains only the
// operands the current MFMA window needs, leaving the lead reads in flight under the MFMAs.
// Physical LDS rows = row-PAIRS (128 B) with 8-slot XOR swizzle == R8's measured-0-conflict
// geometry: logical (row r, chunk c) -> pair q=r>>1, slot (c + 4*(r&1)) ^ (q&7).
using gcptr = const __attribute__((address_space(1))) void*;
using lptr  = __attribute__((address_space(3))) void*;
#define GLD16(gp, lp) __builtin_amdgcn_global_load_lds((gcptr)(gp), (lptr)(lp), 16, 0, 0)
#define BAR() asm volatile("s_barrier" ::: "memory")
#define LGKM(n) do { asm volatile("s_waitcnt lgkmcnt(" #n ")" ::: "memory"); \
                     __builtin_amdgcn_sched_barrier(0); } while (0)
#define VMW4() asm volatile("s_waitcnt vmcnt(4)" ::: "memory")
#define VMW0() asm volatile("s_waitcnt vmcnt(0)" ::: "memory")

__global__ __launch_bounds__(512, 2) void k_gemm(const uchar* __restrict__ A,
                                                 const uchar* __restrict__ B,
                                                 const float* __restrict__ rs,
                                                 const float* __restrict__ sc,
                                                 const float* __restrict__ zp,
                                                 const float* __restrict__ bias,
                                                 float* __restrict__ C) {
    constexpr int NT = K_DIM / 64;              // 64 K-tiles of BK=64 bytes
    constexpr int NBM = M_DIM / 256;            // 32
    constexpr int NWG = NBM * (N_DIM / 256);    // 1376, % 8 == 0

    __shared__ uchar sA[4][256 * 64];           // 4 x 16 KB
    __shared__ uchar sB[4][256 * 64];           // 4 x 16 KB  (128 KB total)

    // XCD-aware bijective swizzle
    int id = (blockIdx.x & 7) * (NWG / 8) + (blockIdx.x >> 3);
    const int bm = id & (NBM - 1);
    const int bn = id >> 5;

    const int tid = threadIdx.x;
    const int lane = tid & 63;
    const int w  = tid >> 6;     // wave 0..7
    const int wr = w >> 2;       // 0..1 (M): 128 rows each
    const int wc = w & 3;        // 0..3 (N): 64 cols each
    const int l15 = lane & 15;

    // ---- staging source (inverse of the pair-interleave swizzle) ----
    // GLD16 instr: lane l -> pair q = w*16 + i*8 + (l>>3), phys slot l&7;
    // slot v = (l&7) ^ ((l>>3)&7) -> src row = 2q + (v>>2), src 16B-chunk = v&3.
    const int v   = (lane & 7) ^ ((lane >> 3) & 7);
    const int srow = w * 32 + 2 * (lane >> 3) + (v >> 2);
    const int scol = (v & 3) * 16;
    const uchar* aBase = A + (size_t)(bm * 256 + srow) * K_DIM + scol;
    const uchar* bBase = B + (size_t)(bn * 256 + srow) * K_DIM + scol;

#define STAGE_A(g, s) do { if ((g) < NT) { \
        const uchar* _s = aBase + (size_t)(g) * 64; \
        uchar* _d = &sA[s][w * 2048]; \
        GLD16(_s, _d); GLD16(_s + (size_t)16 * K_DIM, _d + 1024); } } while (0)
#define STAGE_B(g, s) do { if ((g) < NT) { \
        const uchar* _s = bBase + (size_t)(g) * 64; \
        uchar* _d = &sB[s][w * 2048]; \
        GLD16(_s, _d); GLD16(_s + (size_t)16 * K_DIM, _d + 1024); } } while (0)

    // ---- frag-read addressing (lane-constant; 0-conflict geometry) ----
    // logical row R = frag_base + l15, chunk cb = lane>>4:
    // byte = (R>>1)*128 + ((cb + 4*(R&1)) ^ ((R>>1)&7))*16 ; frag_base multiples of 16.
    const int pc = ((lane >> 4) + 4 * (l15 & 1)) ^ ((l15 >> 1) & 7);
    const int fragOff = (l15 >> 1) * 128 + pc * 16;

    i32x4 aF0[4], aF1[4];      // A m-frags 0-3 / 4-7 of current tile
    i32x4 bF[4];               // all 4 B n-frags of current tile
    i32x4 acc[8][4];
#pragma unroll
    for (int j = 0; j < 8; ++j)
#pragma unroll
        for (int i = 0; i < 4; ++i) acc[j][i] = (i32x4){0, 0, 0, 0};

#define LDA0(b) do { _Pragma("unroll") for (int jj = 0; jj < 4; ++jj) \
        aF0[jj] = *(const i32x4*)&sA[b][wr * 8192 + jj * 1024 + fragOff]; } while (0)
#define LDA1(b) do { _Pragma("unroll") for (int jj = 0; jj < 4; ++jj) \
        aF1[jj] = *(const i32x4*)&sA[b][wr * 8192 + 4096 + jj * 1024 + fragOff]; } while (0)
#define LDB4(b) do { _Pragma("unroll") for (int ii = 0; ii < 4; ++ii) \
        bF[ii] = *(const i32x4*)&sB[b][wc * 4096 + ii * 1024 + fragOff]; } while (0)

#define MFMA_W(af, jbase) do { \
    __builtin_amdgcn_s_setprio(1); \
    _Pragma("unroll") for (int jj = 0; jj < 4; ++jj) \
    _Pragma("unroll") for (int ii = 0; ii < 4; ++ii) \
        acc[(jbase) + jj][ii] = __builtin_amdgcn_mfma_i32_16x16x64_i8( \
            af[jj], bF[ii], acc[(jbase) + jj][ii], 0, 0, 0); \
    __builtin_amdgcn_s_setprio(0); \
    __builtin_amdgcn_sched_barrier(0); \
    } while (0)

    // ---- prologue: stage tiles 0,1,2; publish t0,t1; primer reads for tile 0 ----
    STAGE_A(0, 0); STAGE_B(0, 0);
    STAGE_A(1, 1); STAGE_B(1, 1);
    STAGE_A(2, 2); STAGE_B(2, 2);
    VMW4();          // drains t0,t1 (t2's 4 stay in flight)
    BAR();
    LDA0(0); LDB4(0);            // "W2(-1)" primer: 8 reads

    // ---- main loop: 2 windows/tile, reads lead one window, counted lgkm ----
#define TILE(g, b) do { \
    /* W1: MFMA m0-3 (aF0,bF) */ \
    LDA1(b);                                   /* 4 reads: aF1(g) */ \
    STAGE_A((g) + 3, ((b) + 3) & 3); \
    LGKM(4);                                   /* drain aF0(g), bF(g); keep aF1 in flight */ \
    MFMA_W(aF0, 0); \
    BAR(); \
    /* W2: MFMA m4-7 (aF1,bF) */ \
    STAGE_B((g) + 3, ((b) + 3) & 3); \
    if ((g) + 1 < NT) { LDA0(((b) + 1) & 3);   /* 4 reads: aF0(g+1), resident since t-1 */ \
                        LGKM(4); }             /* drain aF1(g); keep aF0' in flight */ \
    else              { LGKM(0); } \
    MFMA_W(aF1, 4); \
    if ((g) + 1 < NT) LDB4(((b) + 1) & 3);     /* bF(g+1) AFTER MFMA (bF reg WAR) */ \
    if ((g) + 3 >= NT) { VMW0(); } else { VMW4(); }  /* publish tile g+2 */ \
    BAR(); \
    } while (0)

    for (int g = 0; g < NT; g += 4) {
        TILE(g, 0);
        TILE(g + 1, 1);
        TILE(g + 2, 2);
        TILE(g + 3, 3);
    }

    // ---- epilogue: y = fs*S - fz*RS[row] + bias ----
    const float inv = 1.0f / XSCALE;
    float fsv[4], fzv[4], bvv[4];
    int colv[4];
#pragma unroll
    for (int i = 0; i < 4; ++i) {
        colv[i] = bn * 256 + wc * 64 + i * 16 + l15;
        fsv[i] = sc[colv[i]] * inv;
        fzv[i] = fsv[i] * zp[colv[i]];
        bvv[i] = bias[colv[i]];
    }
#pragma unroll
    for (int j = 0; j < 8; ++j) {
        const int rowbase = bm * 256 + wr * 128 + j * 16 + ((lane >> 4) << 2);
#pragma unroll
        for (int r = 0; r < 4; ++r) {
            const int row = rowbase + r;
            const float rsv = rs[row];
            float* cp = C + (size_t)row * N_DIM;
#pragma unroll
            for (int i = 0; i < 4; ++i)
                cp[colv[i]] = fsv[i] * (float)acc[j][i][r] - fzv[i] * rsv + bvv[i];
        }
    }
#undef TILE
#undef MFMA_W
#undef LDA0
#undef LDA1
#undef LDB4
#undef STAGE_A
#undef STAGE_B
}

// ---------- fallback (ws too small): classic 16x16 fp32 tiled GEMM ----------
__global__ __launch_bounds__(256) void k_fb(const float* __restrict__ x, const int* __restrict__ q,
                                            const float* __restrict__ sc, const float* __restrict__ zp,
                                            const float* __restrict__ bias, float* __restrict__ C) {
    __shared__ float sX[16][17];
    __shared__ float sW[16][17];
    int tx = threadIdx.x & 15, ty = threadIdx.x >> 4;
    int m0 = blockIdx.y * 16, n0 = blockIdx.x * 16;
    int o = n0 + ty;
    float s = sc[o], z = zp[o];
    float acc = 0.f;
    for (int k0 = 0; k0 < K_DIM; k0 += 16) {
        sX[ty][tx] = x[(size_t)(m0 + ty) * K_DIM + k0 + tx];
        sW[ty][tx] = ((float)q[(size_t)o * K_DIM + k0 + tx] - z) * s;
        __syncthreads();
#pragma unroll
        for (int kk = 0; kk < 16; ++kk) acc += sX[ty][kk] * sW[tx][kk];
        __syncthreads();
    }
    C[(size_t)(m0 + ty) * N_DIM + n0 + tx] = acc + bias[n0 + tx];
}

extern "C" void kernel_launch(void* const* d_in, const int* in_sizes, int n_in,
                              void* d_out, int out_size, void* d_ws, size_t ws_size,
                              hipStream_t stream) {
    const float* x    = (const float*)d_in[0];
    const int*   qw   = (const int*)d_in[1];
    const float* sc   = (const float*)d_in[2];
    const float* zp   = (const float*)d_in[3];
    const float* bias = (const float*)d_in[4];
    float* out = (float*)d_out;

    const size_t xq_bytes = (size_t)M_DIM * K_DIM;        // 33,554,432
    const size_t wq_bytes = (size_t)N_DIM * K_DIM;        // 45,088,768
    const size_t rs_bytes = (size_t)M_DIM * 4;            // 32,768
    if (ws_size >= xq_bytes + wq_bytes + rs_bytes) {
        uchar* xq = (uchar*)d_ws;
        uchar* wq = xq + xq_bytes;
        float* rs = (float*)(wq + wq_bytes);
        k_quant_x<<<M_DIM, 256, 0, stream>>>((const float4*)x, (int4*)xq, rs);
        k_pack_w<<<N_DIM, 256, 0, stream>>>((const int4*)qw, (int4*)wq);
        k_gemm<<<(M_DIM / 256) * (N_DIM / 256), 512, 0, stream>>>(xq, wq, rs, sc, zp, bias, out);
    } else {
        dim3 g(N_DIM / 16, M_DIM / 16);
        k_fb<<<g, 256, 0, stream>>>(x, qw, sc, zp, bias, out);
    }
}

// Round 11
// 522.991 us; speedup vs baseline: 1.1114x; 1.1114x over previous
//
#include <hip/hip_runtime.h>

#define M_DIM 8192
#define K_DIM 4096
#define N_DIM 11008
#define XSCALE 20.0f

typedef int i32x4  __attribute__((ext_vector_type(4)));
typedef unsigned char uchar;

// ---------- pre-pass 1: x fp32 -> i8 (round(x*20), clamp +-127) + exact int row sums ----------
__global__ __launch_bounds__(256) void k_quant_x(const float4* __restrict__ x,
                                                 int4* __restrict__ xq,
                                                 float* __restrict__ rs) {
    __shared__ int sred[4];
    const int row = blockIdx.x;
    const int t = threadIdx.x;
    const float4* src = x + (size_t)row * (K_DIM / 4) + t * 4;
    int o[4];
    int acc = 0;
#pragma unroll
    for (int c = 0; c < 4; ++c) {
        float4 v = src[c];
        int b0 = __float2int_rn(fmaxf(fminf(v.x * XSCALE, 127.f), -127.f));
        int b1 = __float2int_rn(fmaxf(fminf(v.y * XSCALE, 127.f), -127.f));
        int b2 = __float2int_rn(fmaxf(fminf(v.z * XSCALE, 127.f), -127.f));
        int b3 = __float2int_rn(fmaxf(fminf(v.w * XSCALE, 127.f), -127.f));
        acc += b0 + b1 + b2 + b3;
        o[c] = (b0 & 255) | ((b1 & 255) << 8) | ((b2 & 255) << 16) | ((b3 & 255) << 24);
    }
    xq[(size_t)row * 256 + t] = make_int4(o[0], o[1], o[2], o[3]);
#pragma unroll
    for (int off = 32; off >= 1; off >>= 1) acc += __shfl_down(acc, off);
    if ((t & 63) == 0) sred[t >> 6] = acc;
    __syncthreads();
    if (t == 0) rs[row] = (float)(sred[0] + sred[1] + sred[2] + sred[3]);
}

// ---------- pre-pass 2: qweight int32 (0..15) -> packed i8 ----------
__global__ __launch_bounds__(256) void k_pack_w(const int4* __restrict__ q, int4* __restrict__ wq) {
    size_t i = (size_t)blockIdx.x * 256 + threadIdx.x;   // 16 elems per thread
    int4 a = q[i * 4], b = q[i * 4 + 1], c = q[i * 4 + 2], d = q[i * 4 + 3];
    int4 o;
    o.x = a.x | (a.y << 8) | (a.z << 16) | (a.w << 24);
    o.y = b.x | (b.y << 8) | (b.z << 16) | (b.w << 24);
    o.z = c.x | (c.y << 8) | (c.z << 16) | (c.w << 24);
    o.w = d.x | (d.y << 8) | (d.z << 16) | (d.w << 24);
    wq[i] = o;
}

// ---------- 256x256 i8 GEMM, BK=128, mfma_i32_16x16x64_i8, TWO 32-MFMA windows/K-tile ----------
// S[m][n] = sum_k X[m][k]*Q[n][k] (exact);  y = (s/20)*S - (s*zp/20)*RS[m] + bias
// Window = {reads for THIS window's MFMAs ; stage next-tile halves} -> BAR -> lgkm(0) ->
//          32 MFMA (setprio-bracketed) -> VMW -> BAR
// Per-wave load ring (verified): W1(t) issues A1h(t+1) [2]; W2(t) issues A0/B0/B1(t+2) [6].
// VMW8 at W1(t) end drains A1h(t) (read at W2(t)); at W2(t) end drains A0B0B1(t+1)
// (read at W1(t+1)). Steady-state outstanding = 8; never drains to 0 until tail (g>=NT-3).
// LDS: 128-B rows; 16B chunk c of row r stores global chunk c ^ (r&7) (0 conflicts, measured R8).
using gcptr = const __attribute__((address_space(1))) void*;
using lptr  = __attribute__((address_space(3))) void*;
#define GLD16(gp, lp) __builtin_amdgcn_global_load_lds((gcptr)(gp), (lptr)(lp), 16, 0, 0)
#define BAR() asm volatile("s_barrier" ::: "memory")
#define LGKM0() do { asm volatile("s_waitcnt lgkmcnt(0)" ::: "memory"); \
                     __builtin_amdgcn_sched_barrier(0); } while (0)
#define VMW8() asm volatile("s_waitcnt vmcnt(8)" ::: "memory")
#define VMW6() asm volatile("s_waitcnt vmcnt(6)" ::: "memory")
#define VMW0() asm volatile("s_waitcnt vmcnt(0)" ::: "memory")

__global__ __launch_bounds__(512, 2) void k_gemm(const uchar* __restrict__ A,
                                                 const uchar* __restrict__ B,
                                                 const float* __restrict__ rs,
                                                 const float* __restrict__ sc,
                                                 const float* __restrict__ zp,
                                                 const float* __restrict__ bias,
                                                 float* __restrict__ C) {
    constexpr int NT = K_DIM / 128;             // 32 K-tiles of BK=128 bytes
    constexpr int NBM = M_DIM / 256;            // 32
    constexpr int NWG = NBM * (N_DIM / 256);    // 1376, % 8 == 0

    __shared__ uchar sA[2][256 * 128];          // 2 x 32 KB
    __shared__ uchar sB[2][256 * 128];          // 2 x 32 KB  (128 KB total)

    // XCD-aware bijective swizzle
    int id = (blockIdx.x & 7) * (NWG / 8) + (blockIdx.x >> 3);
    const int bm = id & (NBM - 1);
    const int bn = id >> 5;

    const int tid = threadIdx.x;
    const int lane = tid & 63;
    const int w  = tid >> 6;     // wave 0..7
    const int wr = w >> 2;       // 0..1 (M)
    const int wc = w & 3;        // 0..3 (N)

    // ---- staging source (pre-swizzled global chunk: c_src = c_lds ^ (row&7), 16B chunks) ----
    const int trow = tid >> 3;                                   // 0..63
    const int scol = ((tid & 7) ^ (trow & 7)) * 16;              // byte col
    const uchar* aBase = A + (size_t)(bm * 256 + trow) * K_DIM + scol;
    const uchar* bBase = B + (size_t)(bn * 256 + trow) * K_DIM + scol;
    const int ldsW = w * 1024;                                   // wave-uniform dest (bytes)

#define STAGE_A(kt, H, sbuf) do { if ((kt) < NT) { \
        const uchar* _s = aBase + (size_t)((H) * 128) * K_DIM + (kt) * 128; \
        uchar* _d = &sA[sbuf][(H) * 16384 + ldsW]; \
        GLD16(_s, _d); GLD16(_s + (size_t)64 * K_DIM, _d + 8192); } } while (0)
#define STAGE_B(kt, H, sbuf) do { if ((kt) < NT) { \
        const uchar* _s = bBase + (size_t)((H) * 128) * K_DIM + (kt) * 128; \
        uchar* _d = &sB[sbuf][(H) * 16384 + ldsW]; \
        GLD16(_s, _d); GLD16(_s + (size_t)64 * K_DIM, _d + 8192); } } while (0)

    // ---- ds_read lane addressing (swizzled, 16-row frags; R8 zero-conflict geometry) ----
    const int rowAb = (wr * 16 + (lane & 15)) * 128;   // byte offset of lane's row
    const int rowBb = (wc * 16 + (lane & 15)) * 128;
    const int cb  = lane >> 4;                         // chunk selector 0..3
    const int swz = lane & 7;                          // row&7 for this lane
#define CHUNK(ks) ((((ks) * 4 + cb) ^ swz) * 16)

    i32x4 aF[4][2];            // current A-half: 4 m-frags x 2 ks
    i32x4 bF[2][2][2];         // BOTH B-halves: nh x 2 ii x 2 ks
    i32x4 acc[8][4];           // 8 m-frags x 4 n-frags (16x16 each)
#pragma unroll
    for (int j = 0; j < 8; ++j)
#pragma unroll
        for (int i = 0; i < 4; ++i) acc[j][i] = (i32x4){0, 0, 0, 0};

#define LDA(mh, buf) do { \
    _Pragma("unroll") for (int jj = 0; jj < 4; ++jj) \
    _Pragma("unroll") for (int ks = 0; ks < 2; ++ks) \
        aF[jj][ks] = *(const i32x4*)&sA[buf][(mh) * 16384 + jj * 4096 + rowAb + CHUNK(ks)]; \
    } while (0)
#define LDB(nh, buf) do { \
    _Pragma("unroll") for (int ii = 0; ii < 2; ++ii) \
    _Pragma("unroll") for (int ks = 0; ks < 2; ++ks) \
        bF[nh][ii][ks] = *(const i32x4*)&sB[buf][(nh) * 16384 + ii * 8192 + rowBb + CHUNK(ks)]; \
    } while (0)
    // 32-MFMA half-tile window: ks outer (16 indep MFMAs before ks=1 partners; dep dist 16)
#define MFMA_H(mh) do { \
    __builtin_amdgcn_s_setprio(1); \
    _Pragma("unroll") for (int ks = 0; ks < 2; ++ks) \
    _Pragma("unroll") for (int jj = 0; jj < 4; ++jj) \
    _Pragma("unroll") for (int nh = 0; nh < 2; ++nh) \
    _Pragma("unroll") for (int ii = 0; ii < 2; ++ii) \
        acc[(mh) * 4 + jj][nh * 2 + ii] = __builtin_amdgcn_mfma_i32_16x16x64_i8( \
            aF[jj][ks], bF[nh][ii][ks], acc[(mh) * 4 + jj][nh * 2 + ii], 0, 0, 0); \
    __builtin_amdgcn_s_setprio(0); \
    __builtin_amdgcn_sched_barrier(0); \
    } while (0)

    // ---- prologue: stage t0 fully (8) + t1's A0,B0,B1 (6); publish t0 ----
    STAGE_A(0, 0, 0); STAGE_B(0, 0, 0); STAGE_B(0, 1, 0); STAGE_A(0, 1, 0);
    STAGE_A(1, 0, 1); STAGE_B(1, 0, 1); STAGE_B(1, 1, 1);
    VMW6();          // drains t0's 8; t1's 6 in flight
    BAR();

    // ---- main loop: 2 windows per K-tile ----
#define TILE(g, buf) do { \
    /* W1: quadrants (0,0)+(0,1) -- needs A0, B0, B1 of tile g */ \
    LDA(0, buf); LDB(0, buf); LDB(1, buf);      /* 16 ds_reads */ \
    STAGE_A((g) + 1, 1, (buf) ^ 1);             /* A1h(g+1): target read at W2(g-1), drained */ \
    BAR(); \
    LGKM0(); \
    MFMA_H(0); \
    if ((g) >= NT - 3) { VMW0(); } else { VMW8(); }   /* drains A1h(g) for W2 */ \
    BAR(); \
    /* W2: quadrants (1,1)+(1,0) -- needs A1 of tile g */ \
    LDA(1, buf);                                /* 8 ds_reads */ \
    STAGE_A((g) + 2, 0, buf); STAGE_B((g) + 2, 0, buf); STAGE_B((g) + 2, 1, buf); \
    BAR(); \
    LGKM0(); \
    MFMA_H(1); \
    if ((g) >= NT - 3) { VMW0(); } else { VMW8(); }   /* drains A0B0B1(g+1) for W1(g+1) */ \
    BAR(); \
    } while (0)

    for (int g = 0; g < NT; g += 2) {
        TILE(g, 0);
        TILE(g + 1, 1);
    }

    // ---- epilogue: y = fs*S - fz*RS[row] + bias ----
    const float inv = 1.0f / XSCALE;
    float fsv[4], fzv[4], bvv[4];
    int colv[4];
#pragma unroll
    for (int i = 0; i < 4; ++i) {
        colv[i] = bn * 256 + 16 * wc + 64 * i + (lane & 15);
        fsv[i] = sc[colv[i]] * inv;
        fzv[i] = fsv[i] * zp[colv[i]];
        bvv[i] = bias[colv[i]];
    }
#pragma unroll
    for (int j = 0; j < 8; ++j) {
        const int rowbase = bm * 256 + 16 * wr + 32 * j + ((lane >> 4) << 2);
#pragma unroll
        for (int r = 0; r < 4; ++r) {
            const int row = rowbase + r;
            const float rsv = rs[row];
            float* cp = C + (size_t)row * N_DIM;
#pragma unroll
            for (int i = 0; i < 4; ++i)
                cp[colv[i]] = fsv[i] * (float)acc[j][i][r] - fzv[i] * rsv + bvv[i];
        }
    }
#undef TILE
#undef MFMA_H
#undef LDA
#undef LDB
#undef CHUNK
#undef STAGE_A
#undef STAGE_B
}

// ---------- fallback (ws too small): classic 16x16 fp32 tiled GEMM ----------
__global__ __launch_bounds__(256) void k_fb(const float* __restrict__ x, const int* __restrict__ q,
                                            const float* __restrict__ sc, const float* __restrict__ zp,
                                            const float* __restrict__ bias, float* __restrict__ C) {
    __shared__ float sX[16][17];
    __shared__ float sW[16][17];
    int tx = threadIdx.x & 15, ty = threadIdx.x >> 4;
    int m0 = blockIdx.y * 16, n0 = blockIdx.x * 16;
    int o = n0 + ty;
    float s = sc[o], z = zp[o];
    float acc = 0.f;
    for (int k0 = 0; k0 < K_DIM; k0 += 16) {
        sX[ty][tx] = x[(size_t)(m0 + ty) * K_DIM + k0 + tx];
        sW[ty][tx] = ((float)q[(size_t)o * K_DIM + k0 + tx] - z) * s;
        __syncthreads();
#pragma unroll
        for (int kk = 0; kk < 16; ++kk) acc += sX[ty][kk] * sW[tx][kk];
        __syncthreads();
    }
    C[(size_t)(m0 + ty) * N_DIM + n0 + tx] = acc + bias[n0 + tx];
}

extern "C" void kernel_launch(void* const* d_in, const int* in_sizes, int n_in,
                              void* d_out, int out_size, void* d_ws, size_t ws_size,
                              hipStream_t stream) {
    const float* x    = (const float*)d_in[0];
    const int*   qw   = (const int*)d_in[1];
    const float* sc   = (const float*)d_in[2];
    const float* zp   = (const float*)d_in[3];
    const float* bias = (const float*)d_in[4];
    float* out = (float*)d_out;

    const size_t xq_bytes = (size_t)M_DIM * K_DIM;        // 33,554,432
    const size_t wq_bytes = (size_t)N_DIM * K_DIM;        // 45,088,768
    const size_t rs_bytes = (size_t)M_DIM * 4;            // 32,768
    if (ws_size >= xq_bytes + wq_bytes + rs_bytes) {
        uchar* xq = (uchar*)d_ws;
        uchar* wq = xq + xq_bytes;
        float* rs = (float*)(wq + wq_bytes);
        k_quant_x<<<M_DIM, 256, 0, stream>>>((const float4*)x, (int4*)xq, rs);
        k_pack_w<<<N_DIM, 256, 0, stream>>>((const int4*)qw, (int4*)wq);
        k_gemm<<<(M_DIM / 256) * (N_DIM / 256), 512, 0, stream>>>(xq, wq, rs, sc, zp, bias, out);
    } else {
        dim3 g(N_DIM / 16, M_DIM / 16);
        k_fb<<<g, 256, 0, stream>>>(x, qw, sc, zp, bias, out);
    }
}

// Round 12
// 499.631 us; speedup vs baseline: 1.1633x; 1.0468x over previous
//
#include <hip/hip_runtime.h>

#define M_DIM 8192
#define K_DIM 4096
#define N_DIM 11008
#define XSCALE 20.0f

typedef int i32x4  __attribute__((ext_vector_type(4)));
typedef unsigned char uchar;

// ---------- pre-pass 1: x fp32 -> i8 (round(x*20), clamp +-127) + exact int row sums ----------
__global__ __launch_bounds__(256) void k_quant_x(const float4* __restrict__ x,
                                                 int4* __restrict__ xq,
                                                 float* __restrict__ rs) {
    __shared__ int sred[4];
    const int row = blockIdx.x;
    const int t = threadIdx.x;
    const float4* src = x + (size_t)row * (K_DIM / 4) + t * 4;
    int o[4];
    int acc = 0;
#pragma unroll
    for (int c = 0; c < 4; ++c) {
        float4 v = src[c];
        int b0 = __float2int_rn(fmaxf(fminf(v.x * XSCALE, 127.f), -127.f));
        int b1 = __float2int_rn(fmaxf(fminf(v.y * XSCALE, 127.f), -127.f));
        int b2 = __float2int_rn(fmaxf(fminf(v.z * XSCALE, 127.f), -127.f));
        int b3 = __float2int_rn(fmaxf(fminf(v.w * XSCALE, 127.f), -127.f));
        acc += b0 + b1 + b2 + b3;
        o[c] = (b0 & 255) | ((b1 & 255) << 8) | ((b2 & 255) << 16) | ((b3 & 255) << 24);
    }
    xq[(size_t)row * 256 + t] = make_int4(o[0], o[1], o[2], o[3]);
#pragma unroll
    for (int off = 32; off >= 1; off >>= 1) acc += __shfl_down(acc, off);
    if ((t & 63) == 0) sred[t >> 6] = acc;
    __syncthreads();
    if (t == 0) rs[row] = (float)(sred[0] + sred[1] + sred[2] + sred[3]);
}

// ---------- pre-pass 2: qweight int32 (0..15) -> packed i8 ----------
__global__ __launch_bounds__(256) void k_pack_w(const int4* __restrict__ q, int4* __restrict__ wq) {
    size_t i = (size_t)blockIdx.x * 256 + threadIdx.x;   // 16 elems per thread
    int4 a = q[i * 4], b = q[i * 4 + 1], c = q[i * 4 + 2], d = q[i * 4 + 3];
    int4 o;
    o.x = a.x | (a.y << 8) | (a.z << 16) | (a.w << 24);
    o.y = b.x | (b.y << 8) | (b.z << 16) | (b.w << 24);
    o.z = c.x | (c.y << 8) | (c.z << 16) | (c.w << 24);
    o.w = d.x | (d.y << 8) | (d.z << 16) | (d.w << 24);
    wq[i] = o;
}

// ---------- 128x256 i8 GEMM, BK=64, 3-slot LDS ring, 2 blocks/CU (cross-block TLP) ----------
// S[m][n] = sum_k X[m][k]*Q[n][k] (exact);  y = (s/20)*S - (s*zp/20)*RS[m] + bias
// One barrier per window: {8 ds_reads(tile t) ; 3 GLD16 stage(t+2 -> slot (t+2)%3) ;
//                          lgkm0 ; 16 MFMA (setprio) ; vmcnt(3) ; BAR}
// Ring-of-3 makes WAR single-barrier-safe: slot (t+2)%3's readers (window t-1) all passed
// their lgkm0 before window t-1's closing BAR. vmcnt(3): 6 outstanding -> drain tile t+1.
// Overlap comes from the CO-RESIDENT SECOND BLOCK (no shared barriers), not intra-block
// scheduling -- six intra-block schedule variants all landed 31-44% MfmaUtil.
// LDS pair-interleave swizzle: pair q=row>>1, slot (chunk + 4*(row&1)) ^ (q&7)
// == R10's byte-exact pattern, measured SQ_LDS_BANK_CONFLICT = 0.
using gcptr = const __attribute__((address_space(1))) void*;
using lptr  = __attribute__((address_space(3))) void*;
#define GLD16(gp, lp) __builtin_amdgcn_global_load_lds((gcptr)(gp), (lptr)(lp), 16, 0, 0)
#define BAR() asm volatile("s_barrier" ::: "memory")
#define LGKM0() do { asm volatile("s_waitcnt lgkmcnt(0)" ::: "memory"); \
                     __builtin_amdgcn_sched_barrier(0); } while (0)
#define VMW3() asm volatile("s_waitcnt vmcnt(3)" ::: "memory")
#define VMW0() asm volatile("s_waitcnt vmcnt(0)" ::: "memory")

__global__ __launch_bounds__(512, 4) void k_gemm(const uchar* __restrict__ A,
                                                 const uchar* __restrict__ B,
                                                 const float* __restrict__ rs,
                                                 const float* __restrict__ sc,
                                                 const float* __restrict__ zp,
                                                 const float* __restrict__ bias,
                                                 float* __restrict__ C) {
    constexpr int NT = K_DIM / 64;              // 64 K-tiles of BK=64 bytes
    constexpr int NBM = M_DIM / 128;            // 64
    constexpr int NWG = NBM * (N_DIM / 256);    // 64*43 = 2752, % 8 == 0

    __shared__ uchar lds[3][24576];             // per slot: A 8KB @0, B 16KB @8192

    // XCD-aware bijective swizzle
    int id = (blockIdx.x & 7) * (NWG / 8) + (blockIdx.x >> 3);
    const int bm = id & 63;
    const int bn = id >> 6;

    const int tid = threadIdx.x;
    const int lane = tid & 63;
    const int w  = tid >> 6;     // wave 0..7
    const int wr = w >> 2;       // 0..1 (M): 64 rows each
    const int wc = w & 3;        // 0..3 (N): 64 cols each
    const int l15 = lane & 15;

    // ---- staging source (inverse of the pair-interleave swizzle; R10-proven) ----
    // GLD16 dest: lane l -> local pair p=l>>3, slot s=l&7. v = s ^ (p&7) ->
    // src sub-row = v>>2, src 16B-chunk = v&3.
    const int v    = (lane & 7) ^ ((lane >> 3) & 7);
    const int arow = w * 16 + 2 * (lane >> 3) + (v >> 2);   // A: 16 rows/wave
    const int brow = w * 32 + 2 * (lane >> 3) + (v >> 2);   // B: 32 rows/wave
    const int scol = (v & 3) * 16;
    const uchar* aSrc = A + (size_t)(bm * 128 + arow) * K_DIM + scol;
    const uchar* bSrc = B + (size_t)(bn * 256 + brow) * K_DIM + scol;
    const int aDst = w * 1024;           // A region: 8 waves x 1KB
    const int bDst = 8192 + w * 2048;    // B region: 8 waves x 2KB

#define STAGE(t, s) do { if ((t) < NT) { \
        const size_t _ko = (size_t)(t) * 64; \
        GLD16(aSrc + _ko, &lds[s][aDst]); \
        GLD16(bSrc + _ko, &lds[s][bDst]); \
        GLD16(bSrc + (size_t)16 * K_DIM + _ko, &lds[s][bDst + 1024]); } } while (0)

    // ---- frag-read addressing (R10-proven zero-conflict geometry) ----
    // logical row R = 16*frag + l15, chunk cb = lane>>4 (one b128 = full K=64 slice):
    // byte = (R>>1)*128 + ((cb + 4*(R&1)) ^ ((R>>1)&7))*16 ; 16-row-aligned bases.
    const int pc = ((lane >> 4) + 4 * (l15 & 1)) ^ ((l15 >> 1) & 7);
    const int fragOff = (l15 >> 1) * 128 + pc * 16;

    i32x4 aF[4], bF[4];
    i32x4 acc[4][4];           // 64 AGPR
#pragma unroll
    for (int m = 0; m < 4; ++m)
#pragma unroll
        for (int n = 0; n < 4; ++n) acc[m][n] = (i32x4){0, 0, 0, 0};

#define LDAB(s) do { \
    _Pragma("unroll") for (int mi = 0; mi < 4; ++mi) \
        aF[mi] = *(const i32x4*)&lds[s][wr * 4096 + mi * 1024 + fragOff]; \
    _Pragma("unroll") for (int ni = 0; ni < 4; ++ni) \
        bF[ni] = *(const i32x4*)&lds[s][8192 + wc * 4096 + ni * 1024 + fragOff]; \
    } while (0)

#define MFMA16() do { \
    __builtin_amdgcn_s_setprio(1); \
    _Pragma("unroll") for (int mi = 0; mi < 4; ++mi) \
    _Pragma("unroll") for (int ni = 0; ni < 4; ++ni) \
        acc[mi][ni] = __builtin_amdgcn_mfma_i32_16x16x64_i8(aF[mi], bF[ni], acc[mi][ni], 0, 0, 0); \
    __builtin_amdgcn_s_setprio(0); \
    __builtin_amdgcn_sched_barrier(0); \
    } while (0)

    // ---- prologue: stage tiles 0,1; publish tile 0 ----
    STAGE(0, 0);
    STAGE(1, 1);
    VMW3();          // tile 0's 3 drained; tile 1's 3 in flight
    BAR();

    // ---- main loop: ONE barrier per window ----
    int bR = 0, bS = 2;
    for (int t = 0; t < NT; ++t) {
        LDAB(bR);                 // 8 ds_reads of tile t
        STAGE(t + 2, bS);         // 3 GLD16 into slot (t+2)%3 (dead since window t-1)
        LGKM0();
        MFMA16();
        if (t >= NT - 2) { VMW0(); } else { VMW3(); }   // publish tile t+1
        BAR();
        bR = (bR == 2) ? 0 : bR + 1;
        bS = (bS == 2) ? 0 : bS + 1;
    }

    // ---- epilogue: y = fs*S - fz*RS[row] + bias ----
    const float inv = 1.0f / XSCALE;
    float fsv[4], fzv[4], bvv[4];
    int colv[4];
#pragma unroll
    for (int i = 0; i < 4; ++i) {
        colv[i] = bn * 256 + wc * 64 + i * 16 + l15;
        fsv[i] = sc[colv[i]] * inv;
        fzv[i] = fsv[i] * zp[colv[i]];
        bvv[i] = bias[colv[i]];
    }
#pragma unroll
    for (int mi = 0; mi < 4; ++mi) {
        const int rowbase = bm * 128 + wr * 64 + mi * 16 + ((lane >> 4) << 2);
#pragma unroll
        for (int r = 0; r < 4; ++r) {
            const int row = rowbase + r;
            const float rsv = rs[row];
            float* cp = C + (size_t)row * N_DIM;
#pragma unroll
            for (int i = 0; i < 4; ++i)
                cp[colv[i]] = fsv[i] * (float)acc[mi][i][r] - fzv[i] * rsv + bvv[i];
        }
    }
#undef MFMA16
#undef LDAB
#undef STAGE
}

// ---------- fallback (ws too small): classic 16x16 fp32 tiled GEMM ----------
__global__ __launch_bounds__(256) void k_fb(const float* __restrict__ x, const int* __restrict__ q,
                                            const float* __restrict__ sc, const float* __restrict__ zp,
                                            const float* __restrict__ bias, float* __restrict__ C) {
    __shared__ float sX[16][17];
    __shared__ float sW[16][17];
    int tx = threadIdx.x & 15, ty = threadIdx.x >> 4;
    int m0 = blockIdx.y * 16, n0 = blockIdx.x * 16;
    int o = n0 + ty;
    float s = sc[o], z = zp[o];
    float acc = 0.f;
    for (int k0 = 0; k0 < K_DIM; k0 += 16) {
        sX[ty][tx] = x[(size_t)(m0 + ty) * K_DIM + k0 + tx];
        sW[ty][tx] = ((float)q[(size_t)o * K_DIM + k0 + tx] - z) * s;
        __syncthreads();
#pragma unroll
        for (int kk = 0; kk < 16; ++kk) acc += sX[ty][kk] * sW[tx][kk];
        __syncthreads();
    }
    C[(size_t)(m0 + ty) * N_DIM + n0 + tx] = acc + bias[n0 + tx];
}

extern "C" void kernel_launch(void* const* d_in, const int* in_sizes, int n_in,
                              void* d_out, int out_size, void* d_ws, size_t ws_size,
                              hipStream_t stream) {
    const float* x    = (const float*)d_in[0];
    const int*   qw   = (const int*)d_in[1];
    const float* sc   = (const float*)d_in[2];
    const float* zp   = (const float*)d_in[3];
    const float* bias = (const float*)d_in[4];
    float* out = (float*)d_out;

    const size_t xq_bytes = (size_t)M_DIM * K_DIM;        // 33,554,432
    const size_t wq_bytes = (size_t)N_DIM * K_DIM;        // 45,088,768
    const size_t rs_bytes = (size_t)M_DIM * 4;            // 32,768
    if (ws_size >= xq_bytes + wq_bytes + rs_bytes) {
        uchar* xq = (uchar*)d_ws;
        uchar* wq = xq + xq_bytes;
        float* rs = (float*)(wq + wq_bytes);
        k_quant_x<<<M_DIM, 256, 0, stream>>>((const float4*)x, (int4*)xq, rs);
        k_pack_w<<<N_DIM, 256, 0, stream>>>((const int4*)qw, (int4*)wq);
        k_gemm<<<(M_DIM / 128) * (N_DIM / 256), 512, 0, stream>>>(xq, wq, rs, sc, zp, bias, out);
    } else {
        dim3 g(N_DIM / 16, M_DIM / 16);
        k_fb<<<g, 256, 0, stream>>>(x, qw, sc, zp, bias, out);
    }
}